// Round 1
// baseline (209.401 us; speedup 1.0000x reference)
//
#include <hip/hip_runtime.h>
#include <math.h>

#define S_LEN  2048
#define DMODEL 512
#define NHEADS 8
#define DK     64
#define WIN    64
#define TQ     32          // query rows per attention block

static constexpr float SCALE = 0.125f;   // 1/sqrt(64)

// ---------------------------------------------------------------------------
// Generic NT GEMM: C[M=2048][512] = A[2048][512] @ W[512][512]^T + bias[512]
// 64x64 tile, BK=32, 256 threads, 4x4 microtile, LDS transposed (stride 68).
// ---------------------------------------------------------------------------
__device__ __forceinline__ void gemm_body(const float* __restrict__ A,
                                          const float* __restrict__ W,
                                          const float* __restrict__ bias,
                                          float* __restrict__ C)
{
    __shared__ float As[32][68];   // [k][m]
    __shared__ float Bs[32][68];   // [k][n]
    const int tid  = threadIdx.x;
    const int tx   = tid & 15;     // 0..15 -> 4 cols each
    const int ty   = tid >> 4;     // 0..15 -> 4 rows each
    const int row0 = blockIdx.y * 64;
    const int col0 = blockIdx.x * 64;

    const int sr = tid >> 3;       // 0..31
    const int sc = tid & 7;        // 0..7 (float4 col within k-chunk)

    float acc[4][4] = {};

    for (int k0 = 0; k0 < DMODEL; k0 += 32) {
#pragma unroll
        for (int half = 0; half < 2; ++half) {
            const int rr = sr + 32 * half;
            const float4 av = *(const float4*)(A + (size_t)(row0 + rr) * DMODEL + k0 + sc * 4);
            As[sc * 4 + 0][rr] = av.x;
            As[sc * 4 + 1][rr] = av.y;
            As[sc * 4 + 2][rr] = av.z;
            As[sc * 4 + 3][rr] = av.w;
            const float4 bv = *(const float4*)(W + (size_t)(col0 + rr) * DMODEL + k0 + sc * 4);
            Bs[sc * 4 + 0][rr] = bv.x;
            Bs[sc * 4 + 1][rr] = bv.y;
            Bs[sc * 4 + 2][rr] = bv.z;
            Bs[sc * 4 + 3][rr] = bv.w;
        }
        __syncthreads();
#pragma unroll
        for (int kk = 0; kk < 32; ++kk) {
            const float4 a4 = *(const float4*)&As[kk][ty * 4];
            const float4 b4 = *(const float4*)&Bs[kk][tx * 4];
            const float a[4] = {a4.x, a4.y, a4.z, a4.w};
            const float b[4] = {b4.x, b4.y, b4.z, b4.w};
#pragma unroll
            for (int i = 0; i < 4; ++i)
#pragma unroll
                for (int j = 0; j < 4; ++j)
                    acc[i][j] = fmaf(a[i], b[j], acc[i][j]);
        }
        __syncthreads();
    }

    const float4 bia = *(const float4*)(bias + col0 + tx * 4);
#pragma unroll
    for (int i = 0; i < 4; ++i) {
        float4 o;
        o.x = acc[i][0] + bia.x;
        o.y = acc[i][1] + bia.y;
        o.z = acc[i][2] + bia.z;
        o.w = acc[i][3] + bia.w;
        *(float4*)(C + (size_t)(row0 + ty * 4 + i) * DMODEL + col0 + tx * 4) = o;
    }
}

__global__ __launch_bounds__(256)
void gemm_qkv(const float* __restrict__ x,
              const float* __restrict__ Wq, const float* __restrict__ Wk,
              const float* __restrict__ Wv,
              const float* __restrict__ bq, const float* __restrict__ bk,
              const float* __restrict__ bv,
              float* __restrict__ Qb, float* __restrict__ Kb, float* __restrict__ Vb)
{
    const float* W;
    const float* b;
    float* C;
    if (blockIdx.z == 0)      { W = Wq; b = bq; C = Qb; }
    else if (blockIdx.z == 1) { W = Wk; b = bk; C = Kb; }
    else                      { W = Wv; b = bv; C = Vb; }
    gemm_body(x, W, b, C);
}

__global__ __launch_bounds__(256)
void gemm_out(const float* __restrict__ A, const float* __restrict__ W,
              const float* __restrict__ b, float* __restrict__ C)
{
    gemm_body(A, W, b, C);
}

// ---------------------------------------------------------------------------
// Banded attention, flash-style over three 64-position K/V chunks.
// Block = (head, 32-query tile), 256 threads = 4 waves, 8 rows per wave.
// Online-softmax state (m, l, O) lives in LDS so the row loop stays rolled.
// ---------------------------------------------------------------------------
__global__ __launch_bounds__(256)
void banded_attn(const float* __restrict__ Q,
                 const float* __restrict__ K,
                 const float* __restrict__ V,
                 float* __restrict__ O)
{
    __shared__ float Qs[TQ][68];
    __shared__ float Ks[64][68];
    __shared__ float Vs[64][68];
    __shared__ float Os[TQ][68];
    __shared__ float ms[TQ];
    __shared__ float ls[TQ];

    const int h    = blockIdx.x;
    const int t0   = blockIdx.y * TQ;
    const int tid  = threadIdx.x;
    const int lane = tid & 63;
    const int wv   = tid >> 6;          // 0..3

    // ---- stage Q tile and zero O accumulator: 32 rows x 16 float4 ----
    {
        const int r = tid >> 3;         // 0..31
        const int f = tid & 7;          // 0..7
        const float4* src = (const float4*)(Q + (size_t)(t0 + r) * DMODEL + h * DK);
        float4* qd = (float4*)&Qs[r][0];
        float4* od = (float4*)&Os[r][0];
        const float4 z = {0.f, 0.f, 0.f, 0.f};
#pragma unroll
        for (int c = 0; c < 2; ++c) {
            qd[f + 8 * c] = src[f + 8 * c];
            od[f + 8 * c] = z;
        }
    }
    if (tid < TQ) { ms[tid] = -__builtin_inff(); ls[tid] = 0.f; }

    for (int c = 0; c < 3; ++c) {
        const int p0 = t0 + (c - 1) * 64;
        __syncthreads();    // previous chunk's compute done before restaging
        // ---- stage K/V chunk: 64 rows x 16 float4 each ----
        {
            const int r = tid >> 2;     // 0..63
            const int f = tid & 3;      // 0..3
            const int pos = p0 + r;
            const bool ok = (pos >= 0) && (pos < S_LEN);
            const float4* ks = (const float4*)(K + (size_t)pos * DMODEL + h * DK);
            const float4* vs = (const float4*)(V + (size_t)pos * DMODEL + h * DK);
            float4* kd = (float4*)&Ks[r][0];
            float4* vd = (float4*)&Vs[r][0];
            const float4 z = {0.f, 0.f, 0.f, 0.f};
#pragma unroll
            for (int cc = 0; cc < 4; ++cc) {
                kd[f + 4 * cc] = ok ? ks[f + 4 * cc] : z;
                vd[f + 4 * cc] = ok ? vs[f + 4 * cc] : z;
            }
        }
        __syncthreads();

        for (int rr = 0; rr < 8; ++rr) {
            const int r  = wv * 8 + rr;
            const int qi = t0 + r;
            const int pos = p0 + lane;
            const bool valid = ((unsigned)pos < (unsigned)S_LEN) &&
                               (pos >= qi - WIN) && (pos <= qi + WIN);
            // ---- scores: lane = window position ----
            float s = 0.f;
            const float4* q4 = (const float4*)&Qs[r][0];
            const float4* k4 = (const float4*)&Ks[lane][0];
#pragma unroll
            for (int d = 0; d < 16; ++d) {
                const float4 a = q4[d];
                const float4 b = k4[d];
                s = fmaf(a.x, b.x, s);
                s = fmaf(a.y, b.y, s);
                s = fmaf(a.z, b.z, s);
                s = fmaf(a.w, b.w, s);
            }
            s = valid ? s * SCALE : -__builtin_inff();
            // ---- wave max ----
            float cm = s;
#pragma unroll
            for (int off = 32; off > 0; off >>= 1)
                cm = fmaxf(cm, __shfl_xor(cm, off));
            if (cm > -1e30f) {          // wave-uniform: chunk contributes
                const float mo   = ms[r];
                const float mnew = fmaxf(mo, cm);
                const float alpha = __expf(mo - mnew);   // exp(-inf)=0 on first hit
                const float p = valid ? __expf(s - mnew) : 0.f;
                float ps = p;
#pragma unroll
                for (int off = 32; off > 0; off >>= 1)
                    ps += __shfl_xor(ps, off);
                // ---- PV: lane = head dim; broadcast p_j via shuffle ----
                float a = 0.f;
#pragma unroll
                for (int j = 0; j < 64; ++j) {
                    const float pj = __shfl(p, j);
                    a = fmaf(pj, Vs[j][lane], a);
                }
                Os[r][lane] = Os[r][lane] * alpha + a;
                if (lane == 0) {
                    ms[r] = mnew;
                    ls[r] = ls[r] * alpha + ps;
                }
            }
        }
    }
    __syncthreads();
    // ---- write normalized output ----
#pragma unroll
    for (int rr = 0; rr < 8; ++rr) {
        const int r = wv * 8 + rr;
        O[(size_t)(t0 + r) * DMODEL + h * DK + lane] = Os[r][lane] / ls[r];
    }
}

// ---------------------------------------------------------------------------
extern "C" void kernel_launch(void* const* d_in, const int* in_sizes, int n_in,
                              void* d_out, int out_size, void* d_ws, size_t ws_size,
                              hipStream_t stream)
{
    const float* x  = (const float*)d_in[0];
    const float* Wq = (const float*)d_in[1];
    const float* bq = (const float*)d_in[2];
    const float* Wk = (const float*)d_in[3];
    const float* bk = (const float*)d_in[4];
    const float* Wv = (const float*)d_in[5];
    const float* bv = (const float*)d_in[6];
    const float* Wo = (const float*)d_in[7];
    const float* bo = (const float*)d_in[8];
    float* out = (float*)d_out;

    float* Qb = (float*)d_ws;
    float* Kb = Qb + (size_t)S_LEN * DMODEL;
    float* Vb = Kb + (size_t)S_LEN * DMODEL;
    float* Ab = Vb + (size_t)S_LEN * DMODEL;

    dim3 gq(DMODEL / 64, S_LEN / 64, 3);
    gemm_qkv<<<gq, 256, 0, stream>>>(x, Wq, Wk, Wv, bq, bk, bv, Qb, Kb, Vb);

    dim3 ga(NHEADS, S_LEN / TQ);
    banded_attn<<<ga, 256, 0, stream>>>(Qb, Kb, Vb, Ab);

    dim3 go(DMODEL / 64, S_LEN / 64);
    gemm_out<<<go, 256, 0, stream>>>(Ab, Wo, bo, out);
}

// Round 2
// 188.919 us; speedup vs baseline: 1.1084x; 1.1084x over previous
//
#include <hip/hip_runtime.h>
#include <hip/hip_bf16.h>
#include <math.h>

#define S_LEN  2048
#define DMODEL 512
#define NHEADS 8
#define DK     64
#define WIN    64
#define TQ     32

static constexpr float SCALE = 0.125f;

typedef short bf16x8 __attribute__((ext_vector_type(8)));
typedef float f32x4  __attribute__((ext_vector_type(4)));

// ---------------------------------------------------------------------------
// fp32 -> (bf16 hi, bf16 lo) split
// ---------------------------------------------------------------------------
__device__ __forceinline__ void split1(float v, short& h, short& l)
{
    __hip_bfloat16 hb = __float2bfloat16(v);
    float rest = v - __bfloat162float(hb);
    __hip_bfloat16 lb = __float2bfloat16(rest);
    h = *reinterpret_cast<short*>(&hb);
    l = *reinterpret_cast<short*>(&lb);
}

__device__ __forceinline__ void split4(const float4 v, short4* hp, short4* lp)
{
    short4 h, l;
    split1(v.x, h.x, l.x);
    split1(v.y, h.y, l.y);
    split1(v.z, h.z, l.z);
    split1(v.w, h.w, l.w);
    *hp = h;
    *lp = l;
}

// z selects tensor: 0=x (1M elems), 1..4 = Wq,Wk,Wv,Wo (256K each)
__global__ __launch_bounds__(256)
void cast_split5(const float* __restrict__ x,  const float* __restrict__ wq,
                 const float* __restrict__ wk, const float* __restrict__ wv,
                 const float* __restrict__ wo,
                 short* __restrict__ xh,  short* __restrict__ xl,
                 short* __restrict__ wqh, short* __restrict__ wql,
                 short* __restrict__ wkh, short* __restrict__ wkl,
                 short* __restrict__ wvh, short* __restrict__ wvl,
                 short* __restrict__ woh, short* __restrict__ wol)
{
    const float* s; short* h; short* l; int n4;
    switch (blockIdx.z) {
        case 0:  s = x;  h = xh;  l = xl;  n4 = 262144; break;
        case 1:  s = wq; h = wqh; l = wql; n4 = 65536;  break;
        case 2:  s = wk; h = wkh; l = wkl; n4 = 65536;  break;
        case 3:  s = wv; h = wvh; l = wvl; n4 = 65536;  break;
        default: s = wo; h = woh; l = wol; n4 = 65536;  break;
    }
    for (int i = blockIdx.x * 256 + threadIdx.x; i < n4; i += gridDim.x * 256) {
        const float4 v = ((const float4*)s)[i];
        split4(v, &((short4*)h)[i], &((short4*)l)[i]);
    }
}

__global__ __launch_bounds__(256)
void cast_split1(const float* __restrict__ s, short* __restrict__ h,
                 short* __restrict__ l, int n4)
{
    for (int i = blockIdx.x * 256 + threadIdx.x; i < n4; i += gridDim.x * 256) {
        const float4 v = ((const float4*)s)[i];
        split4(v, &((short4*)h)[i], &((short4*)l)[i]);
    }
}

// ---------------------------------------------------------------------------
// bf16x3 MFMA GEMM: C[m][n] = sum_k A[m][k]*B[n][k] + bias[n]
// A: [M][512] row-major (hi/lo bf16), B: [512][512] row-major (hi/lo bf16).
// Block tile BM x BN, 4 waves in 2x2, wave tile (MT*16) x (NT*16), BK=32.
// Fragment layout (verified, guide §3): A/B: m|n = lane&15, k = quad*8+j;
// C/D: col = lane&15, row = quad*4 + reg.
// ---------------------------------------------------------------------------
template<int BM, int BN, int MT, int NT>
__device__ __forceinline__ void mfma_gemm_body(
    const short* __restrict__ Ahg, const short* __restrict__ Alg,
    const short* __restrict__ Bhg, const short* __restrict__ Blg,
    const float* __restrict__ bias, float* __restrict__ C,
    int row0, int col0)
{
    constexpr int KS = 40;   // LDS row stride (bf16 elems): 16B-aligned rows
    __shared__ short Ah[BM * KS];
    __shared__ short Al[BM * KS];
    __shared__ short Bh[BN * KS];
    __shared__ short Bl[BN * KS];

    const int tid  = threadIdx.x;
    const int lane = tid & 63;
    const int wv   = tid >> 6;
    const int wm0  = (wv >> 1) * (MT * 16);
    const int wn0  = (wv & 1) * (NT * 16);
    const int col  = lane & 15;
    const int quad = lane >> 4;

    f32x4 acc[MT][NT];
#pragma unroll
    for (int i = 0; i < MT; ++i)
#pragma unroll
        for (int j = 0; j < NT; ++j)
            acc[i][j] = (f32x4)0.0f;

    for (int k0 = 0; k0 < 512; k0 += 32) {
        __syncthreads();
        for (int u = tid; u < BM * 4; u += 256) {
            const int r = u >> 2, c = u & 3;
            *(float4*)&Ah[r * KS + c * 8] =
                *(const float4*)(Ahg + (size_t)(row0 + r) * 512 + k0 + c * 8);
            *(float4*)&Al[r * KS + c * 8] =
                *(const float4*)(Alg + (size_t)(row0 + r) * 512 + k0 + c * 8);
        }
        for (int u = tid; u < BN * 4; u += 256) {
            const int r = u >> 2, c = u & 3;
            *(float4*)&Bh[r * KS + c * 8] =
                *(const float4*)(Bhg + (size_t)(col0 + r) * 512 + k0 + c * 8);
            *(float4*)&Bl[r * KS + c * 8] =
                *(const float4*)(Blg + (size_t)(col0 + r) * 512 + k0 + c * 8);
        }
        __syncthreads();

        bf16x8 af_h[MT], af_l[MT], bf_h[NT], bf_l[NT];
#pragma unroll
        for (int i = 0; i < MT; ++i) {
            const int m = wm0 + i * 16 + col;
            af_h[i] = *(const bf16x8*)&Ah[m * KS + quad * 8];
            af_l[i] = *(const bf16x8*)&Al[m * KS + quad * 8];
        }
#pragma unroll
        for (int j = 0; j < NT; ++j) {
            const int n = wn0 + j * 16 + col;
            bf_h[j] = *(const bf16x8*)&Bh[n * KS + quad * 8];
            bf_l[j] = *(const bf16x8*)&Bl[n * KS + quad * 8];
        }
#pragma unroll
        for (int i = 0; i < MT; ++i)
#pragma unroll
            for (int j = 0; j < NT; ++j) {
                acc[i][j] = __builtin_amdgcn_mfma_f32_16x16x32_bf16(af_h[i], bf_h[j], acc[i][j], 0, 0, 0);
                acc[i][j] = __builtin_amdgcn_mfma_f32_16x16x32_bf16(af_h[i], bf_l[j], acc[i][j], 0, 0, 0);
                acc[i][j] = __builtin_amdgcn_mfma_f32_16x16x32_bf16(af_l[i], bf_h[j], acc[i][j], 0, 0, 0);
            }
    }

#pragma unroll
    for (int j = 0; j < NT; ++j) {
        const int cc = col0 + wn0 + j * 16 + col;
        const float bv = bias[cc];
#pragma unroll
        for (int i = 0; i < MT; ++i) {
            const int rbase = row0 + wm0 + i * 16 + quad * 4;
#pragma unroll
            for (int e = 0; e < 4; ++e)
                C[(size_t)(rbase + e) * 512 + cc] = acc[i][j][e] + bv;
        }
    }
}

__global__ __launch_bounds__(256)
void gemm_qkv_mfma(const short* __restrict__ xh, const short* __restrict__ xl,
                   const short* __restrict__ wqh, const short* __restrict__ wql,
                   const short* __restrict__ wkh, const short* __restrict__ wkl,
                   const short* __restrict__ wvh, const short* __restrict__ wvl,
                   const float* __restrict__ bq, const float* __restrict__ bk,
                   const float* __restrict__ bv,
                   float* __restrict__ Qb, float* __restrict__ Kb, float* __restrict__ Vb)
{
    const short *wh, *wl; const float* b; float* C;
    if (blockIdx.z == 0)      { wh = wqh; wl = wql; b = bq; C = Qb; }
    else if (blockIdx.z == 1) { wh = wkh; wl = wkl; b = bk; C = Kb; }
    else                      { wh = wvh; wl = wvl; b = bv; C = Vb; }
    mfma_gemm_body<128, 128, 4, 4>(xh, xl, wh, wl, b, C,
                                   blockIdx.y * 128, blockIdx.x * 128);
}

__global__ __launch_bounds__(256)
void gemm_out_mfma(const short* __restrict__ ah, const short* __restrict__ al,
                   const short* __restrict__ wh, const short* __restrict__ wl,
                   const float* __restrict__ b, float* __restrict__ C)
{
    mfma_gemm_body<64, 64, 2, 2>(ah, al, wh, wl, b, C,
                                 blockIdx.y * 64, blockIdx.x * 64);
}

// ---------------------------------------------------------------------------
// Banded attention (unchanged from round 1)
// ---------------------------------------------------------------------------
__global__ __launch_bounds__(256)
void banded_attn(const float* __restrict__ Q,
                 const float* __restrict__ K,
                 const float* __restrict__ V,
                 float* __restrict__ O)
{
    __shared__ float Qs[TQ][68];
    __shared__ float Ks[64][68];
    __shared__ float Vs[64][68];
    __shared__ float Os[TQ][68];
    __shared__ float ms[TQ];
    __shared__ float ls[TQ];

    const int h    = blockIdx.x;
    const int t0   = blockIdx.y * TQ;
    const int tid  = threadIdx.x;
    const int lane = tid & 63;
    const int wv   = tid >> 6;

    {
        const int r = tid >> 3;
        const int f = tid & 7;
        const float4* src = (const float4*)(Q + (size_t)(t0 + r) * DMODEL + h * DK);
        float4* qd = (float4*)&Qs[r][0];
        float4* od = (float4*)&Os[r][0];
        const float4 z = {0.f, 0.f, 0.f, 0.f};
#pragma unroll
        for (int c = 0; c < 2; ++c) {
            qd[f + 8 * c] = src[f + 8 * c];
            od[f + 8 * c] = z;
        }
    }
    if (tid < TQ) { ms[tid] = -__builtin_inff(); ls[tid] = 0.f; }

    for (int c = 0; c < 3; ++c) {
        const int p0 = t0 + (c - 1) * 64;
        __syncthreads();
        {
            const int r = tid >> 2;
            const int f = tid & 3;
            const int pos = p0 + r;
            const bool ok = (pos >= 0) && (pos < S_LEN);
            const float4* ks = (const float4*)(K + (size_t)pos * DMODEL + h * DK);
            const float4* vs = (const float4*)(V + (size_t)pos * DMODEL + h * DK);
            float4* kd = (float4*)&Ks[r][0];
            float4* vd = (float4*)&Vs[r][0];
            const float4 z = {0.f, 0.f, 0.f, 0.f};
#pragma unroll
            for (int cc = 0; cc < 4; ++cc) {
                kd[f + 4 * cc] = ok ? ks[f + 4 * cc] : z;
                vd[f + 4 * cc] = ok ? vs[f + 4 * cc] : z;
            }
        }
        __syncthreads();

        for (int rr = 0; rr < 8; ++rr) {
            const int r  = wv * 8 + rr;
            const int qi = t0 + r;
            const int pos = p0 + lane;
            const bool valid = ((unsigned)pos < (unsigned)S_LEN) &&
                               (pos >= qi - WIN) && (pos <= qi + WIN);
            float s = 0.f;
            const float4* q4 = (const float4*)&Qs[r][0];
            const float4* k4 = (const float4*)&Ks[lane][0];
#pragma unroll
            for (int d = 0; d < 16; ++d) {
                const float4 a = q4[d];
                const float4 b = k4[d];
                s = fmaf(a.x, b.x, s);
                s = fmaf(a.y, b.y, s);
                s = fmaf(a.z, b.z, s);
                s = fmaf(a.w, b.w, s);
            }
            s = valid ? s * SCALE : -__builtin_inff();
            float cm = s;
#pragma unroll
            for (int off = 32; off > 0; off >>= 1)
                cm = fmaxf(cm, __shfl_xor(cm, off));
            if (cm > -1e30f) {
                const float mo   = ms[r];
                const float mnew = fmaxf(mo, cm);
                const float alpha = __expf(mo - mnew);
                const float p = valid ? __expf(s - mnew) : 0.f;
                float ps = p;
#pragma unroll
                for (int off = 32; off > 0; off >>= 1)
                    ps += __shfl_xor(ps, off);
                float a = 0.f;
#pragma unroll
                for (int j = 0; j < 64; ++j) {
                    const float pj = __shfl(p, j);
                    a = fmaf(pj, Vs[j][lane], a);
                }
                Os[r][lane] = Os[r][lane] * alpha + a;
                if (lane == 0) {
                    ms[r] = mnew;
                    ls[r] = ls[r] * alpha + ps;
                }
            }
        }
    }
    __syncthreads();
#pragma unroll
    for (int rr = 0; rr < 8; ++rr) {
        const int r = wv * 8 + rr;
        O[(size_t)(t0 + r) * DMODEL + h * DK + lane] = Os[r][lane] / ls[r];
    }
}

// ---------------------------------------------------------------------------
extern "C" void kernel_launch(void* const* d_in, const int* in_sizes, int n_in,
                              void* d_out, int out_size, void* d_ws, size_t ws_size,
                              hipStream_t stream)
{
    const float* x  = (const float*)d_in[0];
    const float* Wq = (const float*)d_in[1];
    const float* bq = (const float*)d_in[2];
    const float* Wk = (const float*)d_in[3];
    const float* bk = (const float*)d_in[4];
    const float* Wv = (const float*)d_in[5];
    const float* bv = (const float*)d_in[6];
    const float* Wo = (const float*)d_in[7];
    const float* bo = (const float*)d_in[8];
    float* out = (float*)d_out;

    char* ws = (char*)d_ws;
    float* Qb = (float*)(ws);                       // 4 MB
    float* Kb = (float*)(ws + (4u << 20));          // 4 MB
    float* Vb = (float*)(ws + (8u << 20));          // 4 MB
    float* Ab = (float*)(ws + (12u << 20));         // 4 MB
    short* xh = (short*)(ws + (16u << 20));         // 2 MB
    short* xl = (short*)(ws + (18u << 20));         // 2 MB
    short* wqh = (short*)(ws + (20u << 20));
    short* wql = (short*)(ws + (20u << 20) + (512u << 10));
    short* wkh = (short*)(ws + (21u << 20));
    short* wkl = (short*)(ws + (21u << 20) + (512u << 10));
    short* wvh = (short*)(ws + (22u << 20));
    short* wvl = (short*)(ws + (22u << 20) + (512u << 10));
    short* woh = (short*)(ws + (23u << 20));
    short* wol = (short*)(ws + (23u << 20) + (512u << 10));
    short* abh = xh;   // reuse: xh/xl dead after QKV GEMM
    short* abl = xl;

    dim3 gc(256, 1, 5);
    cast_split5<<<gc, 256, 0, stream>>>(x, Wq, Wk, Wv, Wo,
                                        xh, xl, wqh, wql, wkh, wkl,
                                        wvh, wvl, woh, wol);

    dim3 gq(DMODEL / 128, S_LEN / 128, 3);
    gemm_qkv_mfma<<<gq, 256, 0, stream>>>(xh, xl, wqh, wql, wkh, wkl, wvh, wvl,
                                          bq, bk, bv, Qb, Kb, Vb);

    dim3 ga(NHEADS, S_LEN / TQ);
    banded_attn<<<ga, 256, 0, stream>>>(Qb, Kb, Vb, Ab);

    cast_split1<<<dim3(256), 256, 0, stream>>>(Ab, abh, abl, 262144);

    dim3 go(DMODEL / 64, S_LEN / 64);
    gemm_out_mfma<<<go, 256, 0, stream>>>(abh, abl, woh, wol, bo, out);
}

// Round 3
// 124.979 us; speedup vs baseline: 1.6755x; 1.5116x over previous
//
#include <hip/hip_runtime.h>
#include <hip/hip_bf16.h>
#include <math.h>

#define S_LEN  2048
#define DMODEL 512
#define NHEADS 8
#define DK     64
#define WIN    64

static constexpr float SCALE = 0.125f;

typedef short bf16x8 __attribute__((ext_vector_type(8)));
typedef float f32x4  __attribute__((ext_vector_type(4)));

// ---------------------------------------------------------------------------
// fp32 -> bf16 helpers
// ---------------------------------------------------------------------------
__device__ __forceinline__ short bfh(float v)
{
    __hip_bfloat16 b = __float2bfloat16(v);
    return *reinterpret_cast<short*>(&b);
}
__device__ __forceinline__ float bf2f(short s)
{
    __hip_bfloat16 b = *reinterpret_cast<__hip_bfloat16*>(&s);
    return __bfloat162float(b);
}
__device__ __forceinline__ void split1(float v, short& h, short& l)
{
    h = bfh(v);
    l = bfh(v - bf2f(h));
}
__device__ __forceinline__ void split4(const float4 v, short4* hp, short4* lp)
{
    short4 h, l;
    split1(v.x, h.x, l.x);
    split1(v.y, h.y, l.y);
    split1(v.z, h.z, l.z);
    split1(v.w, h.w, l.w);
    *hp = h;
    *lp = l;
}

// z selects tensor: 0=x (1M elems), 1..4 = Wq,Wk,Wv,Wo (256K each)
__global__ __launch_bounds__(256)
void cast_split5(const float* __restrict__ x,  const float* __restrict__ wq,
                 const float* __restrict__ wk, const float* __restrict__ wv,
                 const float* __restrict__ wo,
                 short* __restrict__ xh,  short* __restrict__ xl,
                 short* __restrict__ wqh, short* __restrict__ wql,
                 short* __restrict__ wkh, short* __restrict__ wkl,
                 short* __restrict__ wvh, short* __restrict__ wvl,
                 short* __restrict__ woh, short* __restrict__ wol)
{
    const float* s; short* h; short* l; int n4;
    switch (blockIdx.z) {
        case 0:  s = x;  h = xh;  l = xl;  n4 = 262144; break;
        case 1:  s = wq; h = wqh; l = wql; n4 = 65536;  break;
        case 2:  s = wk; h = wkh; l = wkl; n4 = 65536;  break;
        case 3:  s = wv; h = wvh; l = wvl; n4 = 65536;  break;
        default: s = wo; h = woh; l = wol; n4 = 65536;  break;
    }
    for (int i = blockIdx.x * 256 + threadIdx.x; i < n4; i += gridDim.x * 256) {
        const float4 v = ((const float4*)s)[i];
        split4(v, &((short4*)h)[i], &((short4*)l)[i]);
    }
}

// ---------------------------------------------------------------------------
// bf16x3 MFMA GEMM: C[m][n] = sum_k A[m][k]*B[n][k] + bias[n]
// ---------------------------------------------------------------------------
template<int BM, int BN, int MT, int NT>
__device__ __forceinline__ void mfma_gemm_body(
    const short* __restrict__ Ahg, const short* __restrict__ Alg,
    const short* __restrict__ Bhg, const short* __restrict__ Blg,
    const float* __restrict__ bias, float* __restrict__ C,
    int row0, int col0)
{
    constexpr int KS = 40;
    __shared__ __align__(16) short Ah[BM * KS];
    __shared__ __align__(16) short Al[BM * KS];
    __shared__ __align__(16) short Bh[BN * KS];
    __shared__ __align__(16) short Bl[BN * KS];

    const int tid  = threadIdx.x;
    const int lane = tid & 63;
    const int wv   = tid >> 6;
    const int wm0  = (wv >> 1) * (MT * 16);
    const int wn0  = (wv & 1) * (NT * 16);
    const int col  = lane & 15;
    const int quad = lane >> 4;

    f32x4 acc[MT][NT];
#pragma unroll
    for (int i = 0; i < MT; ++i)
#pragma unroll
        for (int j = 0; j < NT; ++j)
            acc[i][j] = (f32x4)0.0f;

    for (int k0 = 0; k0 < 512; k0 += 32) {
        __syncthreads();
        for (int u = tid; u < BM * 4; u += 256) {
            const int r = u >> 2, c = u & 3;
            *(float4*)&Ah[r * KS + c * 8] =
                *(const float4*)(Ahg + (size_t)(row0 + r) * 512 + k0 + c * 8);
            *(float4*)&Al[r * KS + c * 8] =
                *(const float4*)(Alg + (size_t)(row0 + r) * 512 + k0 + c * 8);
        }
        for (int u = tid; u < BN * 4; u += 256) {
            const int r = u >> 2, c = u & 3;
            *(float4*)&Bh[r * KS + c * 8] =
                *(const float4*)(Bhg + (size_t)(col0 + r) * 512 + k0 + c * 8);
            *(float4*)&Bl[r * KS + c * 8] =
                *(const float4*)(Blg + (size_t)(col0 + r) * 512 + k0 + c * 8);
        }
        __syncthreads();

        bf16x8 af_h[MT], af_l[MT], bf_h[NT], bf_l[NT];
#pragma unroll
        for (int i = 0; i < MT; ++i) {
            const int m = wm0 + i * 16 + col;
            af_h[i] = *(const bf16x8*)&Ah[m * KS + quad * 8];
            af_l[i] = *(const bf16x8*)&Al[m * KS + quad * 8];
        }
#pragma unroll
        for (int j = 0; j < NT; ++j) {
            const int n = wn0 + j * 16 + col;
            bf_h[j] = *(const bf16x8*)&Bh[n * KS + quad * 8];
            bf_l[j] = *(const bf16x8*)&Bl[n * KS + quad * 8];
        }
#pragma unroll
        for (int i = 0; i < MT; ++i)
#pragma unroll
            for (int j = 0; j < NT; ++j) {
                acc[i][j] = __builtin_amdgcn_mfma_f32_16x16x32_bf16(af_h[i], bf_h[j], acc[i][j], 0, 0, 0);
                acc[i][j] = __builtin_amdgcn_mfma_f32_16x16x32_bf16(af_h[i], bf_l[j], acc[i][j], 0, 0, 0);
                acc[i][j] = __builtin_amdgcn_mfma_f32_16x16x32_bf16(af_l[i], bf_h[j], acc[i][j], 0, 0, 0);
            }
    }

#pragma unroll
    for (int j = 0; j < NT; ++j) {
        const int cc = col0 + wn0 + j * 16 + col;
        const float bv = bias[cc];
#pragma unroll
        for (int i = 0; i < MT; ++i) {
            const int rbase = row0 + wm0 + i * 16 + quad * 4;
#pragma unroll
            for (int e = 0; e < 4; ++e)
                C[(size_t)(rbase + e) * 512 + cc] = acc[i][j][e] + bv;
        }
    }
}

__global__ __launch_bounds__(256)
void gemm_qkv_mfma(const short* __restrict__ xh, const short* __restrict__ xl,
                   const short* __restrict__ wqh, const short* __restrict__ wql,
                   const short* __restrict__ wkh, const short* __restrict__ wkl,
                   const short* __restrict__ wvh, const short* __restrict__ wvl,
                   const float* __restrict__ bq, const float* __restrict__ bk,
                   const float* __restrict__ bv,
                   float* __restrict__ Qb, float* __restrict__ Kb, float* __restrict__ Vb)
{
    const short *wh, *wl; const float* b; float* C;
    if (blockIdx.z == 0)      { wh = wqh; wl = wql; b = bq; C = Qb; }
    else if (blockIdx.z == 1) { wh = wkh; wl = wkl; b = bk; C = Kb; }
    else                      { wh = wvh; wl = wvl; b = bv; C = Vb; }
    mfma_gemm_body<64, 64, 2, 2>(xh, xl, wh, wl, b, C,
                                 blockIdx.y * 64, blockIdx.x * 64);
}

__global__ __launch_bounds__(256)
void gemm_out_mfma(const short* __restrict__ ah, const short* __restrict__ al,
                   const short* __restrict__ wh, const short* __restrict__ wl,
                   const float* __restrict__ b, float* __restrict__ C)
{
    mfma_gemm_body<32, 64, 1, 2>(ah, al, wh, wl, b, C,
                                 blockIdx.y * 32, blockIdx.x * 64);
}

// ---------------------------------------------------------------------------
// MFMA banded attention. Block = (head, 32-query tile), 256 thr = 4 waves.
// Window = 192 staged positions (t0-64 .. t0+127); full softmax, no online.
// S = Q(hi/lo bf16) . K(bf16)^T via MFMA; P split hi/lo; O = P . V(bf16)^T.
// Output written as bf16 hi/lo straight into the out-GEMM input buffers.
// ---------------------------------------------------------------------------
__global__ __launch_bounds__(256)
void banded_attn_mfma(const float* __restrict__ Q,
                      const float* __restrict__ K,
                      const float* __restrict__ V,
                      short* __restrict__ abh, short* __restrict__ abl)
{
    // layout: Vt[64][200] | K[192][72] (aliased later by Ph[32][200],Pl[32][200]) | Qh[32][72] | Ql[32][72]
    __shared__ __align__(16) short smem[64 * 200 + 192 * 72 + 2 * 32 * 72];
    __shared__ float pmax[4][32];
    __shared__ float psum[4][32];
    short* VtS = smem;
    short* KS  = smem + 64 * 200;
    short* QhS = KS + 192 * 72;
    short* QlS = QhS + 32 * 72;
    short* PhS = KS;              // K dead after QK phase
    short* PlS = KS + 32 * 200;

    const int h    = blockIdx.x;
    const int t0   = blockIdx.y * 32;
    const int tid  = threadIdx.x;
    const int lane = tid & 63;
    const int wv   = tid >> 6;
    const int col  = lane & 15;
    const int quad = lane >> 4;

    // ---- stage Q tile (hi/lo) ----
    for (int u = tid; u < 32 * 16; u += 256) {
        const int r = u >> 4, c = u & 15;
        const float4 v = *(const float4*)(Q + (size_t)(t0 + r) * 512 + h * 64 + c * 4);
        short4 hh, ll;
        split4(v, &hh, &ll);
        *(short4*)&QhS[r * 72 + c * 4] = hh;
        *(short4*)&QlS[r * 72 + c * 4] = ll;
    }
    // ---- stage K window (single bf16) ----
    for (int u = tid; u < 192 * 16; u += 256) {
        const int r = u >> 4, c = u & 15;
        const int pos = t0 - 64 + r;
        float4 v = {0.f, 0.f, 0.f, 0.f};
        if (pos >= 0 && pos < S_LEN)
            v = *(const float4*)(K + (size_t)pos * 512 + h * 64 + c * 4);
        short4 kk;
        kk.x = bfh(v.x); kk.y = bfh(v.y); kk.z = bfh(v.z); kk.w = bfh(v.w);
        *(short4*)&KS[r * 72 + c * 4] = kk;
    }
    // ---- stage V window transposed: Vt[dim][pos] (single bf16) ----
#pragma unroll
    for (int ch = 0; ch < 3; ++ch) {
        const int pr  = ch * 64 + lane;
        const int pos = t0 - 64 + pr;
        const bool ok = (pos >= 0) && (pos < S_LEN);
#pragma unroll
        for (int c = 0; c < 4; ++c) {
            const int d0 = wv * 16 + c * 4;
            float4 v = {0.f, 0.f, 0.f, 0.f};
            if (ok) v = *(const float4*)(V + (size_t)pos * 512 + h * 64 + d0);
            VtS[(d0 + 0) * 200 + pr] = bfh(v.x);
            VtS[(d0 + 1) * 200 + pr] = bfh(v.y);
            VtS[(d0 + 2) * 200 + pr] = bfh(v.z);
            VtS[(d0 + 3) * 200 + pr] = bfh(v.w);
        }
    }
    __syncthreads();

    // ---- QK^T: wave covers positions [wv*48, wv*48+48) ----
    f32x4 sacc[2][3];
#pragma unroll
    for (int mi = 0; mi < 2; ++mi)
#pragma unroll
        for (int nj = 0; nj < 3; ++nj)
            sacc[mi][nj] = (f32x4)0.0f;

#pragma unroll
    for (int ks = 0; ks < 2; ++ks) {
        bf16x8 aqh[2], aql[2];
#pragma unroll
        for (int mi = 0; mi < 2; ++mi) {
            aqh[mi] = *(const bf16x8*)&QhS[(mi * 16 + col) * 72 + ks * 32 + quad * 8];
            aql[mi] = *(const bf16x8*)&QlS[(mi * 16 + col) * 72 + ks * 32 + quad * 8];
        }
#pragma unroll
        for (int nj = 0; nj < 3; ++nj) {
            const bf16x8 bk = *(const bf16x8*)&KS[(wv * 48 + nj * 16 + col) * 72 + ks * 32 + quad * 8];
#pragma unroll
            for (int mi = 0; mi < 2; ++mi) {
                sacc[mi][nj] = __builtin_amdgcn_mfma_f32_16x16x32_bf16(aqh[mi], bk, sacc[mi][nj], 0, 0, 0);
                sacc[mi][nj] = __builtin_amdgcn_mfma_f32_16x16x32_bf16(aql[mi], bk, sacc[mi][nj], 0, 0, 0);
            }
        }
    }

    // ---- mask + scale ----
    float pv[2][3][4];
#pragma unroll
    for (int mi = 0; mi < 2; ++mi)
#pragma unroll
        for (int nj = 0; nj < 3; ++nj)
#pragma unroll
            for (int e = 0; e < 4; ++e) {
                const int r32 = mi * 16 + quad * 4 + e;
                const int n   = wv * 48 + nj * 16 + col;
                const int pos = t0 - 64 + n;
                const int d   = n - r32;     // pos - qi + 64
                const bool valid = (pos >= 0) && (pos < S_LEN) && (d >= 0) && (d <= 128);
                pv[mi][nj][e] = valid ? sacc[mi][nj][e] * SCALE : -__builtin_inff();
            }

    // ---- wave-partial row max ----
#pragma unroll
    for (int mi = 0; mi < 2; ++mi)
#pragma unroll
        for (int e = 0; e < 4; ++e) {
            float mx = fmaxf(fmaxf(pv[mi][0][e], pv[mi][1][e]), pv[mi][2][e]);
#pragma unroll
            for (int off = 1; off < 16; off <<= 1)
                mx = fmaxf(mx, __shfl_xor(mx, off));
            if ((lane & 15) == 0) pmax[wv][mi * 16 + quad * 4 + e] = mx;
        }
    __syncthreads();   // pmax complete; also: all K reads done -> P may overwrite

    // ---- exp + wave-partial sums + write P (hi/lo) ----
#pragma unroll
    for (int mi = 0; mi < 2; ++mi)
#pragma unroll
        for (int e = 0; e < 4; ++e) {
            const int r32 = mi * 16 + quad * 4 + e;
            const float m = fmaxf(fmaxf(pmax[0][r32], pmax[1][r32]),
                                  fmaxf(pmax[2][r32], pmax[3][r32]));
            float ss = 0.f;
#pragma unroll
            for (int nj = 0; nj < 3; ++nj) {
                const float p = __expf(pv[mi][nj][e] - m);
                pv[mi][nj][e] = p;
                ss += p;
            }
#pragma unroll
            for (int off = 1; off < 16; off <<= 1)
                ss += __shfl_xor(ss, off);
            if ((lane & 15) == 0) psum[wv][r32] = ss;
#pragma unroll
            for (int nj = 0; nj < 3; ++nj) {
                const int n = wv * 48 + nj * 16 + col;
                const float p = pv[mi][nj][e];
                const short ph = bfh(p);
                PhS[r32 * 200 + n] = ph;
                PlS[r32 * 200 + n] = bfh(p - bf2f(ph));
            }
        }
    __syncthreads();   // P + psum complete

    // ---- PV: wave handles m-tile (wv>>1), n-tiles (wv&1)*2 + {0,1} ----
    const int mi = wv >> 1;
    f32x4 oacc[2];
    oacc[0] = (f32x4)0.0f;
    oacc[1] = (f32x4)0.0f;
#pragma unroll
    for (int ks = 0; ks < 6; ++ks) {
        const bf16x8 pah = *(const bf16x8*)&PhS[(mi * 16 + col) * 200 + ks * 32 + quad * 8];
        const bf16x8 pal = *(const bf16x8*)&PlS[(mi * 16 + col) * 200 + ks * 32 + quad * 8];
#pragma unroll
        for (int t = 0; t < 2; ++t) {
            const int nj = (wv & 1) * 2 + t;
            const bf16x8 vb = *(const bf16x8*)&VtS[(nj * 16 + col) * 200 + ks * 32 + quad * 8];
            oacc[t] = __builtin_amdgcn_mfma_f32_16x16x32_bf16(pah, vb, oacc[t], 0, 0, 0);
            oacc[t] = __builtin_amdgcn_mfma_f32_16x16x32_bf16(pal, vb, oacc[t], 0, 0, 0);
        }
    }

    // ---- epilogue: divide by l, split to bf16 hi/lo, write out-GEMM inputs ----
    float linv[4];
#pragma unroll
    for (int e = 0; e < 4; ++e) {
        const int r32 = mi * 16 + quad * 4 + e;
        const float l = psum[0][r32] + psum[1][r32] + psum[2][r32] + psum[3][r32];
        linv[e] = 1.0f / l;
    }
#pragma unroll
    for (int t = 0; t < 2; ++t) {
        const int nj = (wv & 1) * 2 + t;
#pragma unroll
        for (int e = 0; e < 4; ++e) {
            const int r32 = mi * 16 + quad * 4 + e;
            const float val = oacc[t][e] * linv[e];
            short hh, ll;
            split1(val, hh, ll);
            const size_t idx = (size_t)(t0 + r32) * 512 + h * 64 + nj * 16 + col;
            abh[idx] = hh;
            abl[idx] = ll;
        }
    }
}

// ---------------------------------------------------------------------------
extern "C" void kernel_launch(void* const* d_in, const int* in_sizes, int n_in,
                              void* d_out, int out_size, void* d_ws, size_t ws_size,
                              hipStream_t stream)
{
    const float* x  = (const float*)d_in[0];
    const float* Wq = (const float*)d_in[1];
    const float* bq = (const float*)d_in[2];
    const float* Wk = (const float*)d_in[3];
    const float* bk = (const float*)d_in[4];
    const float* Wv = (const float*)d_in[5];
    const float* bv = (const float*)d_in[6];
    const float* Wo = (const float*)d_in[7];
    const float* bo = (const float*)d_in[8];
    float* out = (float*)d_out;

    char* ws = (char*)d_ws;
    float* Qb = (float*)(ws);                       // 4 MB
    float* Kb = (float*)(ws + (4u << 20));          // 4 MB
    float* Vb = (float*)(ws + (8u << 20));          // 4 MB
    short* xh = (short*)(ws + (16u << 20));         // 2 MB
    short* xl = (short*)(ws + (18u << 20));         // 2 MB
    short* wqh = (short*)(ws + (20u << 20));
    short* wql = (short*)(ws + (20u << 20) + (512u << 10));
    short* wkh = (short*)(ws + (21u << 20));
    short* wkl = (short*)(ws + (21u << 20) + (512u << 10));
    short* wvh = (short*)(ws + (22u << 20));
    short* wvl = (short*)(ws + (22u << 20) + (512u << 10));
    short* woh = (short*)(ws + (23u << 20));
    short* wol = (short*)(ws + (23u << 20) + (512u << 10));
    short* abh = xh;   // xh/xl dead after QKV GEMM; attention writes here
    short* abl = xl;

    dim3 gc(256, 1, 5);
    cast_split5<<<gc, 256, 0, stream>>>(x, Wq, Wk, Wv, Wo,
                                        xh, xl, wqh, wql, wkh, wkl,
                                        wvh, wvl, woh, wol);

    dim3 gq(DMODEL / 64, S_LEN / 64, 3);            // 768 blocks
    gemm_qkv_mfma<<<gq, 256, 0, stream>>>(xh, xl, wqh, wql, wkh, wkl, wvh, wvl,
                                          bq, bk, bv, Qb, Kb, Vb);

    dim3 ga(NHEADS, S_LEN / 32);                    // 512 blocks
    banded_attn_mfma<<<ga, 256, 0, stream>>>(Qb, Kb, Vb, abh, abl);

    dim3 go(DMODEL / 64, S_LEN / 32);               // 512 blocks
    gemm_out_mfma<<<go, 256, 0, stream>>>(abh, abl, woh, wol, bo, out);
}

// Round 4
// 118.585 us; speedup vs baseline: 1.7658x; 1.0539x over previous
//
#include <hip/hip_runtime.h>
#include <hip/hip_bf16.h>
#include <math.h>

#define S_LEN  2048
#define DMODEL 512
#define NHEADS 8
#define DK     64
#define WIN    64

static constexpr float SCALE = 0.125f;

typedef short bf16x8 __attribute__((ext_vector_type(8)));
typedef float f32x4  __attribute__((ext_vector_type(4)));

// ---------------------------------------------------------------------------
// helpers
// ---------------------------------------------------------------------------
__device__ __forceinline__ short bfh(float v)
{
    __hip_bfloat16 b = __float2bfloat16(v);
    return *reinterpret_cast<short*>(&b);
}
__device__ __forceinline__ float bf2f(short s)
{
    __hip_bfloat16 b = *reinterpret_cast<__hip_bfloat16*>(&s);
    return __bfloat162float(b);
}
__device__ __forceinline__ void split1(float v, short& h, short& l)
{
    h = bfh(v);
    l = bfh(v - bf2f(h));
}

// async global->LDS, 16B per lane; lds dest = wave-uniform base + lane*16
__device__ __forceinline__ void dma16(const void* g, void* l)
{
    __builtin_amdgcn_global_load_lds(
        (const __attribute__((address_space(1))) unsigned int*)g,
        (__attribute__((address_space(3))) unsigned int*)l, 16, 0, 0);
}

// ---------------------------------------------------------------------------
// cast kernel: z=0: x -> (xh, xl) split; z=1..4: W -> single bf16
// ---------------------------------------------------------------------------
__global__ __launch_bounds__(256)
void cast_ws(const float* __restrict__ x,  const float* __restrict__ wq,
             const float* __restrict__ wk, const float* __restrict__ wv,
             const float* __restrict__ wo,
             short* __restrict__ xh, short* __restrict__ xl,
             short* __restrict__ wqb, short* __restrict__ wkb,
             short* __restrict__ wvb, short* __restrict__ wob)
{
    const int z = blockIdx.z;
    if (z == 0) {
        for (int i = blockIdx.x * 256 + threadIdx.x; i < 262144; i += gridDim.x * 256) {
            const float4 v = ((const float4*)x)[i];
            short4 h, l;
            split1(v.x, h.x, l.x);
            split1(v.y, h.y, l.y);
            split1(v.z, h.z, l.z);
            split1(v.w, h.w, l.w);
            ((short4*)xh)[i] = h;
            ((short4*)xl)[i] = l;
        }
    } else {
        const float* s; short* d;
        switch (z) {
            case 1:  s = wq; d = wqb; break;
            case 2:  s = wk; d = wkb; break;
            case 3:  s = wv; d = wvb; break;
            default: s = wo; d = wob; break;
        }
        for (int i = blockIdx.x * 256 + threadIdx.x; i < 65536; i += gridDim.x * 256) {
            const float4 v = ((const float4*)s)[i];
            short4 o;
            o.x = bfh(v.x); o.y = bfh(v.y); o.z = bfh(v.z); o.w = bfh(v.w);
            ((short4*)d)[i] = o;
        }
    }
}

// ---------------------------------------------------------------------------
// bf16x2 MFMA GEMM core: acc[m][n] = sum_k (Ah+Al)[m][k] * B[n][k]
// A split hi/lo bf16 [M][512]; B single bf16 [N][512]. BK=32.
// Staging via global_load_lds(16B), unpadded 64B rows, chunk XOR-swizzle
// (chunk ^ (row>>1)&3) => fragment ds_read_b128 at 2-way bank alias (free).
// ---------------------------------------------------------------------------
template<int BM, int BN, int MT, int NT>
__device__ __forceinline__ void gemm2_acc(const short* __restrict__ Ahg,
                                          const short* __restrict__ Alg,
                                          const short* __restrict__ Bg,
                                          int row0, int col0,
                                          f32x4 acc[MT][NT])
{
    __shared__ __align__(16) short sAh[BM * 32];
    __shared__ __align__(16) short sAl[BM * 32];
    __shared__ __align__(16) short sB [BN * 32];

    const int tid  = threadIdx.x;
    const int lane = tid & 63;
    const int wv   = tid >> 6;
    const int col  = lane & 15;
    const int quad = lane >> 4;
    const int wm0  = (wv >> 1) * (MT * 16);
    const int wn0  = (wv & 1) * (NT * 16);
    const int lr   = lane >> 2;      // 0..15 row within 16-row group
    const int lc   = lane & 3;       // 16B chunk slot within row
    constexpr int nIss = (2 * BM + BN) / 16;

#pragma unroll
    for (int i = 0; i < MT; ++i)
#pragma unroll
        for (int j = 0; j < NT; ++j)
            acc[i][j] = (f32x4)0.0f;

    for (int k0 = 0; k0 < 512; k0 += 32) {
        __syncthreads();
        for (int i = wv; i < nIss; i += 4) {
            const short* src; short* dst; int grp, ro;
            if (i < BM / 16)          { grp = i;            src = Ahg; dst = sAh; ro = row0; }
            else if (i < BM / 8)      { grp = i - BM / 16;  src = Alg; dst = sAl; ro = row0; }
            else                      { grp = i - BM / 8;   src = Bg;  dst = sB;  ro = col0; }
            const int r  = grp * 16 + lr;
            const int cs = lc ^ ((r >> 1) & 3);
            dma16(src + (size_t)(ro + r) * 512 + k0 + cs * 8, dst + grp * 512);
        }
        __syncthreads();

        bf16x8 fh[MT], fl[MT], fb[NT];
#pragma unroll
        for (int mi = 0; mi < MT; ++mi) {
            const int m = wm0 + mi * 16 + col;
            const int p = quad ^ ((m >> 1) & 3);
            fh[mi] = *(const bf16x8*)&sAh[m * 32 + p * 8];
            fl[mi] = *(const bf16x8*)&sAl[m * 32 + p * 8];
        }
#pragma unroll
        for (int nj = 0; nj < NT; ++nj) {
            const int n = wn0 + nj * 16 + col;
            const int p = quad ^ ((n >> 1) & 3);
            fb[nj] = *(const bf16x8*)&sB[n * 32 + p * 8];
        }
#pragma unroll
        for (int mi = 0; mi < MT; ++mi)
#pragma unroll
            for (int nj = 0; nj < NT; ++nj) {
                acc[mi][nj] = __builtin_amdgcn_mfma_f32_16x16x32_bf16(fh[mi], fb[nj], acc[mi][nj], 0, 0, 0);
                acc[mi][nj] = __builtin_amdgcn_mfma_f32_16x16x32_bf16(fl[mi], fb[nj], acc[mi][nj], 0, 0, 0);
            }
    }
}

// ---------------------------------------------------------------------------
// QKV GEMM: z=0 -> Q (write bf16 hi/lo), z=1 -> K (bf16), z=2 -> V (bf16)
// ---------------------------------------------------------------------------
__global__ __launch_bounds__(256)
void gemm_qkv2(const short* __restrict__ xh, const short* __restrict__ xl,
               const short* __restrict__ wqb, const short* __restrict__ wkb,
               const short* __restrict__ wvb,
               const float* __restrict__ bq, const float* __restrict__ bk,
               const float* __restrict__ bv,
               short* __restrict__ qh, short* __restrict__ ql,
               short* __restrict__ kb, short* __restrict__ vb)
{
    const int z = blockIdx.z;
    const short* B; const float* bias;
    if (z == 0)      { B = wqb; bias = bq; }
    else if (z == 1) { B = wkb; bias = bk; }
    else             { B = wvb; bias = bv; }
    const int row0 = blockIdx.y * 64, col0 = blockIdx.x * 64;

    f32x4 acc[2][2];
    gemm2_acc<64, 64, 2, 2>(xh, xl, B, row0, col0, acc);

    const int tid  = threadIdx.x;
    const int lane = tid & 63;
    const int wv   = tid >> 6;
    const int col  = lane & 15;
    const int quad = lane >> 4;
    const int wm0  = (wv >> 1) * 32;
    const int wn0  = (wv & 1) * 32;

#pragma unroll
    for (int nj = 0; nj < 2; ++nj) {
        const int cc = col0 + wn0 + nj * 16 + col;
        const float bias_v = bias[cc];
#pragma unroll
        for (int mi = 0; mi < 2; ++mi) {
#pragma unroll
            for (int e = 0; e < 4; ++e) {
                const int row = row0 + wm0 + mi * 16 + quad * 4 + e;
                const float val = acc[mi][nj][e] + bias_v;
                const size_t idx = (size_t)row * 512 + cc;
                if (z == 0) {
                    short hh, ll;
                    split1(val, hh, ll);
                    qh[idx] = hh;
                    ql[idx] = ll;
                } else if (z == 1) {
                    kb[idx] = bfh(val);
                } else {
                    vb[idx] = bfh(val);
                }
            }
        }
    }
}

// ---------------------------------------------------------------------------
// Output projection GEMM: fp32 out
// ---------------------------------------------------------------------------
__global__ __launch_bounds__(256)
void gemm_out2(const short* __restrict__ ah, const short* __restrict__ al,
               const short* __restrict__ wob, const float* __restrict__ bo,
               float* __restrict__ out)
{
    const int row0 = blockIdx.y * 32, col0 = blockIdx.x * 64;
    f32x4 acc[1][2];
    gemm2_acc<32, 64, 1, 2>(ah, al, wob, row0, col0, acc);

    const int tid  = threadIdx.x;
    const int lane = tid & 63;
    const int wv   = tid >> 6;
    const int col  = lane & 15;
    const int quad = lane >> 4;
    const int wm0  = (wv >> 1) * 16;
    const int wn0  = (wv & 1) * 32;

#pragma unroll
    for (int nj = 0; nj < 2; ++nj) {
        const int cc = col0 + wn0 + nj * 16 + col;
        const float bias_v = bo[cc];
#pragma unroll
        for (int e = 0; e < 4; ++e) {
            const int row = row0 + wm0 + quad * 4 + e;
            out[(size_t)row * 512 + cc] = acc[0][nj][e] + bias_v;
        }
    }
}

// ---------------------------------------------------------------------------
// MFMA banded attention. Block = (head, 32-query tile), 256 thr = 4 waves.
// Q (hi/lo bf16) and K (bf16) staged via global_load_lds with XOR(row&7)
// chunk swizzle; V staged transposed via short4 loads. P single bf16.
// ---------------------------------------------------------------------------
__global__ __launch_bounds__(256)
void banded_attn2(const short* __restrict__ qh, const short* __restrict__ ql,
                  const short* __restrict__ kb, const short* __restrict__ vb,
                  short* __restrict__ abh, short* __restrict__ abl)
{
    __shared__ __align__(16) short VtS[64 * 200];   // V^T [dim][pos], stride 200
    __shared__ __align__(16) short KS [192 * 64];   // K window, swizzled; aliased by P
    __shared__ __align__(16) short QhS[32 * 64];
    __shared__ __align__(16) short QlS[32 * 64];
    __shared__ float pmax[4][32];
    __shared__ float psum[4][32];
    short* PS = KS;                                 // P [32][200], after QK phase

    const int h    = blockIdx.x;
    const int t0   = blockIdx.y * 32;
    const int tid  = threadIdx.x;
    const int lane = tid & 63;
    const int wv   = tid >> 6;
    const int col  = lane & 15;
    const int quad = lane >> 4;

    // ---- DMA staging: Qh (4 groups), Ql (4), K (24) — 8-row groups of 128B ----
    {
        const int lr = lane >> 3;   // row in group
        const int lc = lane & 7;    // 16B chunk slot
        for (int i = wv; i < 32; i += 4) {
            const short* src; short* dst; int r;
            if (i < 4) {
                r = i * 8 + lr;
                src = qh + (size_t)(t0 + r) * 512 + h * 64;
                dst = QhS + i * 512;
            } else if (i < 8) {
                const int g = i - 4;
                r = g * 8 + lr;
                src = ql + (size_t)(t0 + r) * 512 + h * 64;
                dst = QlS + g * 512;
            } else {
                const int g = i - 8;
                r = g * 8 + lr;
                int pos = t0 - 64 + r;
                pos = pos < 0 ? 0 : (pos > 2047 ? 2047 : pos);   // clamp; masked later
                src = kb + (size_t)pos * 512 + h * 64;
                dst = KS + g * 512;
            }
            const int cs = lc ^ (r & 7);
            dma16(src + cs * 8, dst);
        }
    }
    // ---- V transposed staging (bf16 source) ----
#pragma unroll
    for (int ch = 0; ch < 3; ++ch) {
        const int pr  = ch * 64 + lane;
        int pos = t0 - 64 + pr;
        pos = pos < 0 ? 0 : (pos > 2047 ? 2047 : pos);
#pragma unroll
        for (int c = 0; c < 4; ++c) {
            const int d0 = wv * 16 + c * 4;
            const short4 v = *(const short4*)(vb + (size_t)pos * 512 + h * 64 + d0);
            VtS[(d0 + 0) * 200 + pr] = v.x;
            VtS[(d0 + 1) * 200 + pr] = v.y;
            VtS[(d0 + 2) * 200 + pr] = v.z;
            VtS[(d0 + 3) * 200 + pr] = v.w;
        }
    }
    __syncthreads();

    // ---- QK^T: wave covers positions [wv*48, wv*48+48) ----
    f32x4 sacc[2][3];
#pragma unroll
    for (int mi = 0; mi < 2; ++mi)
#pragma unroll
        for (int nj = 0; nj < 3; ++nj)
            sacc[mi][nj] = (f32x4)0.0f;

#pragma unroll
    for (int ks = 0; ks < 2; ++ks) {
        const int q0 = ks * 4 + quad;
        bf16x8 aqh[2], aql[2];
#pragma unroll
        for (int mi = 0; mi < 2; ++mi) {
            const int m = mi * 16 + col;
            const int p = q0 ^ (m & 7);
            aqh[mi] = *(const bf16x8*)&QhS[m * 64 + p * 8];
            aql[mi] = *(const bf16x8*)&QlS[m * 64 + p * 8];
        }
#pragma unroll
        for (int nj = 0; nj < 3; ++nj) {
            const int n = wv * 48 + nj * 16 + col;
            const int p = q0 ^ (n & 7);
            const bf16x8 bkf = *(const bf16x8*)&KS[n * 64 + p * 8];
#pragma unroll
            for (int mi = 0; mi < 2; ++mi) {
                sacc[mi][nj] = __builtin_amdgcn_mfma_f32_16x16x32_bf16(aqh[mi], bkf, sacc[mi][nj], 0, 0, 0);
                sacc[mi][nj] = __builtin_amdgcn_mfma_f32_16x16x32_bf16(aql[mi], bkf, sacc[mi][nj], 0, 0, 0);
            }
        }
    }

    // ---- mask + scale ----
    float pv[2][3][4];
#pragma unroll
    for (int mi = 0; mi < 2; ++mi)
#pragma unroll
        for (int nj = 0; nj < 3; ++nj)
#pragma unroll
            for (int e = 0; e < 4; ++e) {
                const int r32 = mi * 16 + quad * 4 + e;
                const int n   = wv * 48 + nj * 16 + col;
                const int pos = t0 - 64 + n;
                const int d   = n - r32;
                const bool valid = (pos >= 0) && (pos < S_LEN) && (d >= 0) && (d <= 128);
                pv[mi][nj][e] = valid ? sacc[mi][nj][e] * SCALE : -__builtin_inff();
            }

    // ---- wave-partial row max ----
#pragma unroll
    for (int mi = 0; mi < 2; ++mi)
#pragma unroll
        for (int e = 0; e < 4; ++e) {
            float mx = fmaxf(fmaxf(pv[mi][0][e], pv[mi][1][e]), pv[mi][2][e]);
#pragma unroll
            for (int off = 1; off < 16; off <<= 1)
                mx = fmaxf(mx, __shfl_xor(mx, off));
            if ((lane & 15) == 0) pmax[wv][mi * 16 + quad * 4 + e] = mx;
        }
    __syncthreads();   // pmax done; K/Q reads done -> P may overwrite KS

    // ---- exp + wave-partial sums + write P (single bf16) ----
#pragma unroll
    for (int mi = 0; mi < 2; ++mi)
#pragma unroll
        for (int e = 0; e < 4; ++e) {
            const int r32 = mi * 16 + quad * 4 + e;
            const float m = fmaxf(fmaxf(pmax[0][r32], pmax[1][r32]),
                                  fmaxf(pmax[2][r32], pmax[3][r32]));
            float ss = 0.f;
#pragma unroll
            for (int nj = 0; nj < 3; ++nj) {
                const float p = __expf(pv[mi][nj][e] - m);
                pv[mi][nj][e] = p;
                ss += p;
            }
#pragma unroll
            for (int off = 1; off < 16; off <<= 1)
                ss += __shfl_xor(ss, off);
            if ((lane & 15) == 0) psum[wv][r32] = ss;
#pragma unroll
            for (int nj = 0; nj < 3; ++nj) {
                const int n = wv * 48 + nj * 16 + col;
                PS[r32 * 200 + n] = bfh(pv[mi][nj][e]);
            }
        }
    __syncthreads();

    // ---- PV ----
    const int mi = wv >> 1;
    f32x4 oacc[2];
    oacc[0] = (f32x4)0.0f;
    oacc[1] = (f32x4)0.0f;
#pragma unroll
    for (int ks = 0; ks < 6; ++ks) {
        const bf16x8 pa = *(const bf16x8*)&PS[(mi * 16 + col) * 200 + ks * 32 + quad * 8];
#pragma unroll
        for (int t = 0; t < 2; ++t) {
            const int nj = (wv & 1) * 2 + t;
            const bf16x8 vf = *(const bf16x8*)&VtS[(nj * 16 + col) * 200 + ks * 32 + quad * 8];
            oacc[t] = __builtin_amdgcn_mfma_f32_16x16x32_bf16(pa, vf, oacc[t], 0, 0, 0);
        }
    }

    // ---- epilogue: normalize, split to bf16 hi/lo for out-GEMM ----
    float linv[4];
#pragma unroll
    for (int e = 0; e < 4; ++e) {
        const int r32 = mi * 16 + quad * 4 + e;
        linv[e] = 1.0f / (psum[0][r32] + psum[1][r32] + psum[2][r32] + psum[3][r32]);
    }
#pragma unroll
    for (int t = 0; t < 2; ++t) {
        const int nj = (wv & 1) * 2 + t;
#pragma unroll
        for (int e = 0; e < 4; ++e) {
            const int r32 = mi * 16 + quad * 4 + e;
            const float val = oacc[t][e] * linv[e];
            short hh, ll;
            split1(val, hh, ll);
            const size_t idx = (size_t)(t0 + r32) * 512 + h * 64 + nj * 16 + col;
            abh[idx] = hh;
            abl[idx] = ll;
        }
    }
}

// ---------------------------------------------------------------------------
extern "C" void kernel_launch(void* const* d_in, const int* in_sizes, int n_in,
                              void* d_out, int out_size, void* d_ws, size_t ws_size,
                              hipStream_t stream)
{
    const float* x  = (const float*)d_in[0];
    const float* Wq = (const float*)d_in[1];
    const float* bq = (const float*)d_in[2];
    const float* Wk = (const float*)d_in[3];
    const float* bk = (const float*)d_in[4];
    const float* Wv = (const float*)d_in[5];
    const float* bv = (const float*)d_in[6];
    const float* Wo = (const float*)d_in[7];
    const float* bo = (const float*)d_in[8];
    float* out = (float*)d_out;

    char* ws = (char*)d_ws;
    short* qh  = (short*)(ws);                          // 2 MB
    short* ql  = (short*)(ws + (2u << 20));             // 2 MB
    short* kb  = (short*)(ws + (4u << 20));             // 2 MB
    short* vb  = (short*)(ws + (6u << 20));             // 2 MB
    short* xh  = (short*)(ws + (8u << 20));             // 2 MB
    short* xl  = (short*)(ws + (10u << 20));            // 2 MB
    short* wqb = (short*)(ws + (12u << 20));            // 0.5 MB each
    short* wkb = (short*)(ws + (12u << 20) + 1 * (512u << 10));
    short* wvb = (short*)(ws + (12u << 20) + 2 * (512u << 10));
    short* wob = (short*)(ws + (12u << 20) + 3 * (512u << 10));
    short* abh = xh;    // xh/xl dead after QKV GEMM; attention writes here
    short* abl = xl;

    dim3 gc(128, 1, 5);
    cast_ws<<<gc, 256, 0, stream>>>(x, Wq, Wk, Wv, Wo,
                                    xh, xl, wqb, wkb, wvb, wob);

    dim3 gq(DMODEL / 64, S_LEN / 64, 3);                // 768 blocks
    gemm_qkv2<<<gq, 256, 0, stream>>>(xh, xl, wqb, wkb, wvb,
                                      bq, bk, bv, qh, ql, kb, vb);

    dim3 ga(NHEADS, S_LEN / 32);                        // 512 blocks
    banded_attn2<<<ga, 256, 0, stream>>>(qh, ql, kb, vb, abh, abl);

    dim3 go(DMODEL / 64, S_LEN / 32);                   // 512 blocks
    gemm_out2<<<go, 256, 0, stream>>>(abh, abl, wob, bo, out);
}

// Round 5
// 114.773 us; speedup vs baseline: 1.8245x; 1.0332x over previous
//
#include <hip/hip_runtime.h>
#include <hip/hip_bf16.h>
#include <math.h>

#define S_LEN  2048
#define DMODEL 512
#define NHEADS 8
#define DK     64
#define WIN    64

static constexpr float SCALE = 0.125f;

typedef short bf16x8 __attribute__((ext_vector_type(8)));
typedef float f32x4  __attribute__((ext_vector_type(4)));

// ---------------------------------------------------------------------------
// helpers
// ---------------------------------------------------------------------------
__device__ __forceinline__ short bfh(float v)
{
    __hip_bfloat16 b = __float2bfloat16(v);
    return *reinterpret_cast<short*>(&b);
}
__device__ __forceinline__ float bf2f(short s)
{
    __hip_bfloat16 b = *reinterpret_cast<__hip_bfloat16*>(&s);
    return __bfloat162float(b);
}
__device__ __forceinline__ void split1(float v, short& h, short& l)
{
    h = bfh(v);
    l = bfh(v - bf2f(h));
}

// async global->LDS, 16B per lane; lds dest = wave-uniform base + lane*16
__device__ __forceinline__ void dma16(const void* g, void* l)
{
    __builtin_amdgcn_global_load_lds(
        (const __attribute__((address_space(1))) unsigned int*)g,
        (__attribute__((address_space(3))) unsigned int*)l, 16, 0, 0);
}

// ---------------------------------------------------------------------------
// cast kernel: z=0: x -> (xh, xl) split; z=1..4: W -> single bf16
// ---------------------------------------------------------------------------
__global__ __launch_bounds__(256)
void cast_ws(const float* __restrict__ x,  const float* __restrict__ wq,
             const float* __restrict__ wk, const float* __restrict__ wv,
             const float* __restrict__ wo,
             short* __restrict__ xh, short* __restrict__ xl,
             short* __restrict__ wqb, short* __restrict__ wkb,
             short* __restrict__ wvb, short* __restrict__ wob)
{
    const int z = blockIdx.z;
    if (z == 0) {
        for (int i = blockIdx.x * 256 + threadIdx.x; i < 262144; i += gridDim.x * 256) {
            const float4 v = ((const float4*)x)[i];
            short4 h, l;
            split1(v.x, h.x, l.x);
            split1(v.y, h.y, l.y);
            split1(v.z, h.z, l.z);
            split1(v.w, h.w, l.w);
            ((short4*)xh)[i] = h;
            ((short4*)xl)[i] = l;
        }
    } else {
        const float* s; short* d;
        switch (z) {
            case 1:  s = wq; d = wqb; break;
            case 2:  s = wk; d = wkb; break;
            case 3:  s = wv; d = wvb; break;
            default: s = wo; d = wob; break;
        }
        for (int i = blockIdx.x * 256 + threadIdx.x; i < 65536; i += gridDim.x * 256) {
            const float4 v = ((const float4*)s)[i];
            short4 o;
            o.x = bfh(v.x); o.y = bfh(v.y); o.z = bfh(v.z); o.w = bfh(v.w);
            ((short4*)d)[i] = o;
        }
    }
}

// ---------------------------------------------------------------------------
// Streaming bf16x2 GEMM, barrier-light:
//  - B tile (64 cols x 512 k, bf16) staged in TWO one-shot LDS phases (32 KB),
//    chunk XOR-swizzled so fragment ds_read_b128 is 2-way (free).
//  - A (hi/lo bf16) read straight from global into MFMA fragments:
//    lane pattern (m=lane&15, k=quad*8+j) = 16 rows x 64B coalesced loads.
//  - No per-K-step barriers: compiler pipelines A loads with vmcnt.
// 128 threads = 2 waves; wave covers 32 rows (QKV) or 16 rows (out-proj).
// ---------------------------------------------------------------------------
__global__ __launch_bounds__(128)
void gemm_qkv3(const short* __restrict__ xh, const short* __restrict__ xl,
               const short* __restrict__ wqb, const short* __restrict__ wkb,
               const short* __restrict__ wvb,
               const float* __restrict__ bq, const float* __restrict__ bk,
               const float* __restrict__ bv,
               short* __restrict__ qh, short* __restrict__ ql,
               short* __restrict__ kb, short* __restrict__ vbt)
{
    __shared__ __align__(16) short sB[64 * 256];   // 64 cols x 256 k (one phase)

    const int z = blockIdx.z;
    const short* Bg   = (z == 0) ? wqb : (z == 1) ? wkb : wvb;
    const float* bias = (z == 0) ? bq  : (z == 1) ? bk  : bv;
    const int row0 = blockIdx.y * 64;
    const int col0 = blockIdx.x * 64;
    const int tid  = threadIdx.x;
    const int lane = tid & 63;
    const int wv   = tid >> 6;
    const int col  = lane & 15;
    const int quad = lane >> 4;

    f32x4 acc[2][4];
#pragma unroll
    for (int mi = 0; mi < 2; ++mi)
#pragma unroll
        for (int nj = 0; nj < 4; ++nj)
            acc[mi][nj] = (f32x4)0.0f;

    for (int ph = 0; ph < 2; ++ph) {
        __syncthreads();   // previous phase's LDS reads complete
        for (int i = wv; i < 32; i += 2) {
            const int q = i * 64 + lane;     // dest 16B chunk index
            const int r = q >> 5;            // B row (0..63)
            const int b = q & 31;            // chunk within row
            const int j = b ^ (r & 7);       // source chunk (swizzle low 3 bits)
            dma16(Bg + (size_t)(col0 + r) * 512 + ph * 256 + j * 8, sB + i * 512);
        }
        __syncthreads();   // DMA drained (compiler vmcnt(0) before barrier)

#pragma unroll
        for (int kc = 0; kc < 8; ++kc) {
            const int k = ph * 256 + kc * 32;
            bf16x8 ah[2], al[2];
#pragma unroll
            for (int mi = 0; mi < 2; ++mi) {
                const int m = row0 + wv * 32 + mi * 16 + col;
                ah[mi] = *(const bf16x8*)(xh + (size_t)m * 512 + k + quad * 8);
                al[mi] = *(const bf16x8*)(xl + (size_t)m * 512 + k + quad * 8);
            }
#pragma unroll
            for (int nj = 0; nj < 4; ++nj) {
                const int n = nj * 16 + col;
                const int j = (kc * 4 + quad) ^ (n & 7);
                const bf16x8 bf = *(const bf16x8*)&sB[n * 256 + j * 8];
#pragma unroll
                for (int mi = 0; mi < 2; ++mi) {
                    acc[mi][nj] = __builtin_amdgcn_mfma_f32_16x16x32_bf16(ah[mi], bf, acc[mi][nj], 0, 0, 0);
                    acc[mi][nj] = __builtin_amdgcn_mfma_f32_16x16x32_bf16(al[mi], bf, acc[mi][nj], 0, 0, 0);
                }
            }
        }
    }

    // epilogue: z=0 -> Q hi/lo; z=1 -> K bf16; z=2 -> V^T bf16 [dim][pos]
#pragma unroll
    for (int nj = 0; nj < 4; ++nj) {
        const int cc = col0 + nj * 16 + col;
        const float bias_v = bias[cc];
#pragma unroll
        for (int mi = 0; mi < 2; ++mi) {
#pragma unroll
            for (int e = 0; e < 4; ++e) {
                const int row = row0 + wv * 32 + mi * 16 + quad * 4 + e;
                const float val = acc[mi][nj][e] + bias_v;
                if (z == 0) {
                    short hh, ll;
                    split1(val, hh, ll);
                    qh[(size_t)row * 512 + cc] = hh;
                    ql[(size_t)row * 512 + cc] = ll;
                } else if (z == 1) {
                    kb[(size_t)row * 512 + cc] = bfh(val);
                } else {
                    vbt[(size_t)cc * 2048 + row] = bfh(val);   // transposed
                }
            }
        }
    }
}

__global__ __launch_bounds__(128)
void gemm_out3(const short* __restrict__ ah_g, const short* __restrict__ al_g,
               const short* __restrict__ wob, const float* __restrict__ bo,
               float* __restrict__ out)
{
    __shared__ __align__(16) short sB[64 * 256];

    const int row0 = blockIdx.y * 32;
    const int col0 = blockIdx.x * 64;
    const int tid  = threadIdx.x;
    const int lane = tid & 63;
    const int wv   = tid >> 6;
    const int col  = lane & 15;
    const int quad = lane >> 4;

    f32x4 acc[4];
#pragma unroll
    for (int nj = 0; nj < 4; ++nj)
        acc[nj] = (f32x4)0.0f;

    for (int ph = 0; ph < 2; ++ph) {
        __syncthreads();
        for (int i = wv; i < 32; i += 2) {
            const int q = i * 64 + lane;
            const int r = q >> 5;
            const int b = q & 31;
            const int j = b ^ (r & 7);
            dma16(wob + (size_t)(col0 + r) * 512 + ph * 256 + j * 8, sB + i * 512);
        }
        __syncthreads();

#pragma unroll
        for (int kc = 0; kc < 8; ++kc) {
            const int k = ph * 256 + kc * 32;
            const int m = row0 + wv * 16 + col;
            const bf16x8 ah = *(const bf16x8*)(ah_g + (size_t)m * 512 + k + quad * 8);
            const bf16x8 al = *(const bf16x8*)(al_g + (size_t)m * 512 + k + quad * 8);
#pragma unroll
            for (int nj = 0; nj < 4; ++nj) {
                const int n = nj * 16 + col;
                const int j = (kc * 4 + quad) ^ (n & 7);
                const bf16x8 bf = *(const bf16x8*)&sB[n * 256 + j * 8];
                acc[nj] = __builtin_amdgcn_mfma_f32_16x16x32_bf16(ah, bf, acc[nj], 0, 0, 0);
                acc[nj] = __builtin_amdgcn_mfma_f32_16x16x32_bf16(al, bf, acc[nj], 0, 0, 0);
            }
        }
    }

#pragma unroll
    for (int nj = 0; nj < 4; ++nj) {
        const int cc = col0 + nj * 16 + col;
        const float bias_v = bo[cc];
#pragma unroll
        for (int e = 0; e < 4; ++e) {
            const int row = row0 + wv * 16 + quad * 4 + e;
            out[(size_t)row * 512 + cc] = acc[nj][e] + bias_v;
        }
    }
}

// ---------------------------------------------------------------------------
// MFMA banded attention. Block = (head, 32-query tile), 256 thr = 4 waves.
// Q (hi/lo) and K staged via DMA with XOR(row&7) chunk swizzle.
// V staged from pre-transposed global vbt[dim][pos] via DMA (rows padded to
// 32 chunks in LDS; chunk-swizzled so PV fragment reads are 2-way).
// ---------------------------------------------------------------------------
__global__ __launch_bounds__(256)
void banded_attn3(const short* __restrict__ qh, const short* __restrict__ ql,
                  const short* __restrict__ kb, const short* __restrict__ vbt,
                  short* __restrict__ abh, short* __restrict__ abl)
{
    __shared__ __align__(16) short VtS[64 * 256];   // V^T [dim][32 chunks]
    __shared__ __align__(16) short KS [192 * 64];   // K window; aliased by P
    __shared__ __align__(16) short QhS[32 * 64];
    __shared__ __align__(16) short QlS[32 * 64];
    __shared__ float pmax[4][32];
    __shared__ float psum[4][32];
    short* PS = KS;                                 // P [32][200], after QK

    const int h    = blockIdx.x;
    const int t0   = blockIdx.y * 32;
    const int tid  = threadIdx.x;
    const int lane = tid & 63;
    const int wv   = tid >> 6;
    const int col  = lane & 15;
    const int quad = lane >> 4;

    // ---- DMA staging: Qh (4 issues), Ql (4), K (24) — 8-row groups ----
    {
        const int lr = lane >> 3;
        const int lc = lane & 7;
        for (int i = wv; i < 32; i += 4) {
            const short* src; short* dst; int r;
            if (i < 4) {
                r = i * 8 + lr;
                src = qh + (size_t)(t0 + r) * 512 + h * 64;
                dst = QhS + i * 512;
            } else if (i < 8) {
                const int g = i - 4;
                r = g * 8 + lr;
                src = ql + (size_t)(t0 + r) * 512 + h * 64;
                dst = QlS + g * 512;
            } else {
                const int g = i - 8;
                r = g * 8 + lr;
                int pos = t0 - 64 + r;
                pos = pos < 0 ? 0 : (pos > 2047 ? 2047 : pos);   // clamp; masked later
                src = kb + (size_t)pos * 512 + h * 64;
                dst = KS + g * 512;
            }
            const int cs = lc ^ (r & 7);
            dma16(src + cs * 8, dst);
        }
        // ---- V^T window: 64 dims x 24 chunks (192 pos), rows padded to 32 ----
        for (int i = wv; i < 32; i += 4) {
            const int q = i * 64 + lane;
            const int d = q >> 5;            // dim 0..63
            const int b = q & 31;            // dest chunk in row
            const int j0 = (b < 24) ? b : 0; // dead chunks load dummy
            const int j = j0 ^ (d & 7);      // swizzle low 3 bits (j0<24 closed)
            int p0 = t0 - 64 + j * 8;
            p0 = p0 < 0 ? 0 : (p0 > 2040 ? 2040 : p0);
            dma16(vbt + (size_t)(h * 64 + d) * 2048 + p0, VtS + i * 512);
        }
    }
    __syncthreads();

    // ---- QK^T: wave covers positions [wv*48, wv*48+48) ----
    f32x4 sacc[2][3];
#pragma unroll
    for (int mi = 0; mi < 2; ++mi)
#pragma unroll
        for (int nj = 0; nj < 3; ++nj)
            sacc[mi][nj] = (f32x4)0.0f;

#pragma unroll
    for (int ks = 0; ks < 2; ++ks) {
        const int q0 = ks * 4 + quad;
        bf16x8 aqh[2], aql[2];
#pragma unroll
        for (int mi = 0; mi < 2; ++mi) {
            const int m = mi * 16 + col;
            const int p = q0 ^ (m & 7);
            aqh[mi] = *(const bf16x8*)&QhS[m * 64 + p * 8];
            aql[mi] = *(const bf16x8*)&QlS[m * 64 + p * 8];
        }
#pragma unroll
        for (int nj = 0; nj < 3; ++nj) {
            const int n = wv * 48 + nj * 16 + col;
            const int p = q0 ^ (n & 7);
            const bf16x8 bkf = *(const bf16x8*)&KS[n * 64 + p * 8];
#pragma unroll
            for (int mi = 0; mi < 2; ++mi) {
                sacc[mi][nj] = __builtin_amdgcn_mfma_f32_16x16x32_bf16(aqh[mi], bkf, sacc[mi][nj], 0, 0, 0);
                sacc[mi][nj] = __builtin_amdgcn_mfma_f32_16x16x32_bf16(aql[mi], bkf, sacc[mi][nj], 0, 0, 0);
            }
        }
    }

    // ---- mask + scale ----
    float pv[2][3][4];
#pragma unroll
    for (int mi = 0; mi < 2; ++mi)
#pragma unroll
        for (int nj = 0; nj < 3; ++nj)
#pragma unroll
            for (int e = 0; e < 4; ++e) {
                const int r32 = mi * 16 + quad * 4 + e;
                const int n   = wv * 48 + nj * 16 + col;
                const int pos = t0 - 64 + n;
                const int d   = n - r32;
                const bool valid = (pos >= 0) && (pos < S_LEN) && (d >= 0) && (d <= 128);
                pv[mi][nj][e] = valid ? sacc[mi][nj][e] * SCALE : -__builtin_inff();
            }

    // ---- wave-partial row max ----
#pragma unroll
    for (int mi = 0; mi < 2; ++mi)
#pragma unroll
        for (int e = 0; e < 4; ++e) {
            float mx = fmaxf(fmaxf(pv[mi][0][e], pv[mi][1][e]), pv[mi][2][e]);
#pragma unroll
            for (int off = 1; off < 16; off <<= 1)
                mx = fmaxf(mx, __shfl_xor(mx, off));
            if ((lane & 15) == 0) pmax[wv][mi * 16 + quad * 4 + e] = mx;
        }
    __syncthreads();   // pmax done; K/Q reads done -> P may overwrite KS

    // ---- exp + wave-partial sums + write P (single bf16) ----
#pragma unroll
    for (int mi = 0; mi < 2; ++mi)
#pragma unroll
        for (int e = 0; e < 4; ++e) {
            const int r32 = mi * 16 + quad * 4 + e;
            const float m = fmaxf(fmaxf(pmax[0][r32], pmax[1][r32]),
                                  fmaxf(pmax[2][r32], pmax[3][r32]));
            float ss = 0.f;
#pragma unroll
            for (int nj = 0; nj < 3; ++nj) {
                const float p = __expf(pv[mi][nj][e] - m);
                pv[mi][nj][e] = p;
                ss += p;
            }
#pragma unroll
            for (int off = 1; off < 16; off <<= 1)
                ss += __shfl_xor(ss, off);
            if ((lane & 15) == 0) psum[wv][r32] = ss;
#pragma unroll
            for (int nj = 0; nj < 3; ++nj) {
                const int n = wv * 48 + nj * 16 + col;
                PS[r32 * 200 + n] = bfh(pv[mi][nj][e]);
            }
        }
    __syncthreads();

    // ---- PV ----
    const int mi = wv >> 1;
    f32x4 oacc[2];
    oacc[0] = (f32x4)0.0f;
    oacc[1] = (f32x4)0.0f;
#pragma unroll
    for (int ks = 0; ks < 6; ++ks) {
        const bf16x8 pa = *(const bf16x8*)&PS[(mi * 16 + col) * 200 + ks * 32 + quad * 8];
#pragma unroll
        for (int t = 0; t < 2; ++t) {
            const int d = ((wv & 1) * 2 + t) * 16 + col;
            const int j = (ks * 4 + quad) ^ (d & 7);
            const bf16x8 vf = *(const bf16x8*)&VtS[d * 256 + j * 8];
            oacc[t] = __builtin_amdgcn_mfma_f32_16x16x32_bf16(pa, vf, oacc[t], 0, 0, 0);
        }
    }

    // ---- epilogue: normalize, split to bf16 hi/lo for out-GEMM ----
    float linv[4];
#pragma unroll
    for (int e = 0; e < 4; ++e) {
        const int r32 = mi * 16 + quad * 4 + e;
        linv[e] = 1.0f / (psum[0][r32] + psum[1][r32] + psum[2][r32] + psum[3][r32]);
    }
#pragma unroll
    for (int t = 0; t < 2; ++t) {
        const int nj = (wv & 1) * 2 + t;
#pragma unroll
        for (int e = 0; e < 4; ++e) {
            const int r32 = mi * 16 + quad * 4 + e;
            const float val = oacc[t][e] * linv[e];
            short hh, ll;
            split1(val, hh, ll);
            const size_t idx = (size_t)(t0 + r32) * 512 + h * 64 + nj * 16 + col;
            abh[idx] = hh;
            abl[idx] = ll;
        }
    }
}

// ---------------------------------------------------------------------------
extern "C" void kernel_launch(void* const* d_in, const int* in_sizes, int n_in,
                              void* d_out, int out_size, void* d_ws, size_t ws_size,
                              hipStream_t stream)
{
    const float* x  = (const float*)d_in[0];
    const float* Wq = (const float*)d_in[1];
    const float* bq = (const float*)d_in[2];
    const float* Wk = (const float*)d_in[3];
    const float* bk = (const float*)d_in[4];
    const float* Wv = (const float*)d_in[5];
    const float* bv = (const float*)d_in[6];
    const float* Wo = (const float*)d_in[7];
    const float* bo = (const float*)d_in[8];
    float* out = (float*)d_out;

    char* ws = (char*)d_ws;
    short* qh  = (short*)(ws);                          // 2 MB
    short* ql  = (short*)(ws + (2u << 20));             // 2 MB
    short* kb  = (short*)(ws + (4u << 20));             // 2 MB
    short* vbt = (short*)(ws + (6u << 20));             // 2 MB (transposed V)
    short* xh  = (short*)(ws + (8u << 20));             // 2 MB
    short* xl  = (short*)(ws + (10u << 20));            // 2 MB
    short* wqb = (short*)(ws + (12u << 20));            // 0.5 MB each
    short* wkb = (short*)(ws + (12u << 20) + 1 * (512u << 10));
    short* wvb = (short*)(ws + (12u << 20) + 2 * (512u << 10));
    short* wob = (short*)(ws + (12u << 20) + 3 * (512u << 10));
    short* abh = xh;    // xh/xl dead after QKV GEMM; attention writes here
    short* abl = xl;

    dim3 gc(128, 1, 5);
    cast_ws<<<gc, 256, 0, stream>>>(x, Wq, Wk, Wv, Wo,
                                    xh, xl, wqb, wkb, wvb, wob);

    dim3 gq(DMODEL / 64, S_LEN / 64, 3);                // 8 x 32 x 3 = 768 blocks
    gemm_qkv3<<<gq, 128, 0, stream>>>(xh, xl, wqb, wkb, wvb,
                                      bq, bk, bv, qh, ql, kb, vbt);

    dim3 ga(NHEADS, S_LEN / 32);                        // 512 blocks
    banded_attn3<<<ga, 256, 0, stream>>>(qh, ql, kb, vbt, abh, abl);

    dim3 go(DMODEL / 64, S_LEN / 32);                   // 8 x 64 = 512 blocks
    gemm_out3<<<go, 128, 0, stream>>>(abh, abl, wob, bo, out);
}